// Round 5
// baseline (173.482 us; speedup 1.0000x reference)
//
#include <hip/hip_runtime.h>

typedef __attribute__((ext_vector_type(8))) short short8;
typedef __attribute__((ext_vector_type(4))) float f32x4;
typedef __attribute__((ext_vector_type(2))) float f32x2;
typedef __attribute__((ext_vector_type(2))) unsigned int u32x2;
typedef __attribute__((ext_vector_type(4))) unsigned int u32x4;

#define MFMA16x32(A, B, C) \
  __builtin_amdgcn_mfma_f32_16x16x32_bf16((A), (B), (C), 0, 0, 0)

// Async global->LDS, 16B/lane. Global addr is per-lane; LDS dest is the
// WAVE-UNIFORM base (HW scatters lane i -> base + i*16).
__device__ __forceinline__ void async_cp16(const unsigned short* g, void* l) {
  __builtin_amdgcn_global_load_lds(
      (const __attribute__((address_space(1))) unsigned int*)g,
      (__attribute__((address_space(3))) unsigned int*)l, 16, 0, 0);
}

__device__ __forceinline__ unsigned int fbits(float f) {
  return __builtin_bit_cast(unsigned int, f);
}
// pack two floats -> two bf16 (truncate): low ushort = a, high = b
__device__ __forceinline__ unsigned int pack_bf16(float a, float b) {
  return __builtin_amdgcn_perm(fbits(b), fbits(a), 0x07060302u);
}
__device__ __forceinline__ unsigned short bf16_rne(float f) {
  unsigned int u = fbits(f);
  return (unsigned short)((u + 0x8000u) >> 16);
}
// leaky-relu on a float pair, packed mul (v_pk_mul_f32) + 2 max + 1 perm.
__device__ __forceinline__ unsigned int leaky_pack(float a, float b) {
  f32x2 v = {a, b};
  f32x2 m = v * 0.2f;
  f32x2 r = __builtin_elementwise_max(v, m);
  return pack_bf16(r[0], r[1]);
}

// ---------------------------------------------------------------------------
// Kernel 0 (fused): blocks < 4096: x fp32 -> bf16.  blocks >= 4096: W -> WT
// (bf16, [n][k]) for all three weights.
// ---------------------------------------------------------------------------
__global__ __launch_bounds__(256) void prep_kernel(
    const float* __restrict__ x, unsigned short* __restrict__ xb,
    const float* __restrict__ Wq, const float* __restrict__ Wk,
    const float* __restrict__ Wv, unsigned short* __restrict__ WT) {
  __shared__ float tile[32][33];
  if (blockIdx.x < 4096) {
    const size_t i = ((size_t)blockIdx.x * 256 + threadIdx.x) * 4;
    const float4 f = *(const float4*)(x + i);
    u32x2 u = {(unsigned int)bf16_rne(f.x) | ((unsigned int)bf16_rne(f.y) << 16),
               (unsigned int)bf16_rne(f.z) | ((unsigned int)bf16_rne(f.w) << 16)};
    *(u32x2*)(xb + i) = u;
    return;
  }
  const int bid = blockIdx.x - 4096;
  const int g = bid / 64, rem = bid % 64;
  const int k0 = (rem >> 3) * 32, n0 = (rem & 7) * 32;
  const float* W = (g == 0) ? Wq : (g == 1) ? Wk : Wv;
  const int t = threadIdx.x;
  {
    const int kr = t >> 3, nc = (t & 7) * 4;
    const float4 f = *(const float4*)(W + (size_t)(k0 + kr) * 256 + n0 + nc);
    tile[kr][nc + 0] = f.x; tile[kr][nc + 1] = f.y;
    tile[kr][nc + 2] = f.z; tile[kr][nc + 3] = f.w;
  }
  __syncthreads();
  {
    const int nr = t >> 3, kc = (t & 7) * 4;
    unsigned int u0 = (unsigned int)bf16_rne(tile[kc + 0][nr]) |
                      ((unsigned int)bf16_rne(tile[kc + 1][nr]) << 16);
    unsigned int u1 = (unsigned int)bf16_rne(tile[kc + 2][nr]) |
                      ((unsigned int)bf16_rne(tile[kc + 3][nr]) << 16);
    u32x2 u = {u0, u1};
    *(u32x2*)(WT + (size_t)g * 65536 + (size_t)(n0 + nr) * 256 + k0 + kc) = u;
  }
}

// ---------------------------------------------------------------------------
// Kernel 1: fused QKV projection GEMM, LDS-staged, BK=64 dbuf. 128m x 128n
// tile, 4 waves. Q/K written packed per head: QH/KH[bh][n][32] (Q pre-scaled
// by 1/sqrt(dk)); V written transposed VT[bh*32+d][n] with a key-order
// permutation inside each 32-n group: phys n = s*16+quad*4+r stored at
// n' = (n&~31)|(quad<<3)|(s<<2)|r, so attn's packed S^T registers ARE the
// K=32 MFMA B-fragment (reduction over keys is order-invariant as long as
// P and V use the same key order).
// ---------------------------------------------------------------------------
__global__ __launch_bounds__(256, 2) void proj_kernel(
    const unsigned short* __restrict__ xb, const unsigned short* __restrict__ WT,
    unsigned short* __restrict__ QH, unsigned short* __restrict__ KH,
    unsigned short* __restrict__ VT) {
  __shared__ __align__(16) char smem[65536];  // dbuf x (A 16K + B 16K)
  const int tid = threadIdx.x;
  const int w = tid >> 6, lane = tid & 63, l15 = lane & 15, quad = lane >> 4;
  const int bid = blockIdx.x;
  const int mtile = bid / 6, nt = bid % 6;
  const int g = nt >> 1, n0 = (nt & 1) * 128;
  const int m0 = mtile * 128;

  // Staging: wave w covers tile-rows w*32..+32 (4 instrs of 8 rows each).
  // LDS row r holds global 16B-seg (u ^ (r&7)) at seg u (XOR swizzle).
  const int srow = lane >> 3, useg = lane & 7;
  const int swz = (useg ^ srow) * 8;  // shorts
  const unsigned short* aS = xb + (size_t)(m0 + w * 32 + srow) * 256 + swz;
  const unsigned short* bS =
      WT + (size_t)g * 65536 + (size_t)(n0 + w * 32 + srow) * 256 + swz;

#pragma unroll
  for (int j = 0; j < 4; j++) {  // preload k-tile 0 -> buf 0
    async_cp16(aS + j * 2048, smem + w * 4096 + j * 1024);
    async_cp16(bS + j * 2048, smem + 16384 + w * 4096 + j * 1024);
  }
  __syncthreads();

  const f32x4 zero = {0.f, 0.f, 0.f, 0.f};
  f32x4 acc[2][8];
#pragma unroll
  for (int s = 0; s < 2; s++)
#pragma unroll
    for (int c = 0; c < 8; c++) acc[s][c] = zero;

  const int sw = l15 & 7;
  for (int t = 0; t < 4; t++) {
    const int nb = t & 1;
    const int kn = ((t + 1) & 3) * 64;  // wraps; last prefetch harmless
#pragma unroll
    for (int j = 0; j < 4; j++) {
      async_cp16(aS + kn + j * 2048,
                 smem + (nb ^ 1) * 32768 + w * 4096 + j * 1024);
      async_cp16(bS + kn + j * 2048,
                 smem + (nb ^ 1) * 32768 + 16384 + w * 4096 + j * 1024);
    }
    const char* Ab = smem + nb * 32768;
    const char* Bb = Ab + 16384;
#pragma unroll
    for (int ks = 0; ks < 2; ks++) {
      const int seg = ((ks * 4 + quad) ^ sw) * 16;
      short8 af[2], bf[8];
#pragma unroll
      for (int s = 0; s < 2; s++)
        af[s] = *(const short8*)(Ab + (w * 32 + s * 16 + l15) * 128 + seg);
#pragma unroll
      for (int c = 0; c < 8; c++)
        bf[c] = *(const short8*)(Bb + (c * 16 + l15) * 128 + seg);
      if (g < 2) {
#pragma unroll
        for (int s = 0; s < 2; s++)
#pragma unroll
          for (int c = 0; c < 8; c++)
            acc[s][c] = MFMA16x32(bf[c], af[s], acc[s][c]);  // swapped
      } else {
#pragma unroll
        for (int s = 0; s < 2; s++)
#pragma unroll
          for (int c = 0; c < 8; c++)
            acc[s][c] = MFMA16x32(af[s], bf[c], acc[s][c]);
      }
    }
    __syncthreads();
  }

  if (g < 2) {
    // Swapped orientation: rows m0+w*32+s*16+l15 (seq), cols n0+c*16+quad*4
    // (+reg) = feature -> packed 8B stores into [bh][n][32].
    unsigned short* O = g ? KH : QH;
    const float sc = g ? 1.0f : 0.17677669529663688f;  // 1/sqrt(32) into Q
#pragma unroll
    for (int s = 0; s < 2; s++)
#pragma unroll
      for (int c = 0; c < 8; c++) {
        const int row = m0 + w * 32 + s * 16 + l15;
        const int col = n0 + c * 16 + quad * 4;
        const int bb = row >> 12, nn = row & 4095;
        const int hh = col >> 5, dl = col & 31;
        u32x2 pk = {pack_bf16(acc[s][c][0] * sc, acc[s][c][1] * sc),
                    pack_bf16(acc[s][c][2] * sc, acc[s][c][3] * sc)};
        *(u32x2*)(O + ((size_t)(bb * 8 + hh) * 4096 + nn) * 32 + dl) = pk;
      }
  } else {
    // Natural orientation: reg-dim = 4 consecutive n -> contiguous in VT.
    // Key-permutation: phys n low5 = s*16+quad*4+r stored at quad*8+s*4+r.
#pragma unroll
    for (int s = 0; s < 2; s++)
#pragma unroll
      for (int c = 0; c < 8; c++) {
        const int col = n0 + c * 16 + l15;  // h*32 + d
        const int hh = col >> 5, dl = col & 31;
        const int row = m0 + w * 32 + s * 16 + quad * 4;
        const int bb = row >> 12;
        const int nn = (row & 4064) | (quad << 3) | ((s & 1) << 2);  // &~31
        u32x2 pk = {pack_bf16(acc[s][c][0], acc[s][c][1]),
                    pack_bf16(acc[s][c][2], acc[s][c][3])};
        *(u32x2*)(VT + (size_t)((bb * 8 + hh) * 32 + dl) * 4096 + nn) = pk;
      }
  }
}

// ---------------------------------------------------------------------------
// Kernel 2: attention, split-K. Grid 512 = 32 bh x 16 qh; block = 512
// threads (8 waves). Wave w: key-half khalf=w>>2, q-strip (w&3)*64; wave
// owns 64 q x 32 keys per iter (R4 diagnosis: LDS pipe ~90% busy because
// every wave read the FULL 8KB K+V tiles; split-K halves per-wave LDS reads
// at the same 4-wave/SIMD occupancy). Each wave accumulates a partial O
// over its key-half across all 64 iters; one LDS reduction at the end.
// Staging identical to R4 (waves 0-3 K, 4-7 V, one cp16 each, dbuf 16KB of
// the 32KB smem; the rest is used by the final reduction only).
// ---------------------------------------------------------------------------
__global__ __launch_bounds__(512, 4) void attn_kernel(
    const unsigned short* __restrict__ QH, const unsigned short* __restrict__ KH,
    const unsigned short* __restrict__ VT, float* __restrict__ out) {
  __shared__ __align__(16) char smem[32768];  // [0,16K): dbuf K/V; all: reduce
  const int tid = threadIdx.x;
  const int w = tid >> 6, lane = tid & 63, l15 = lane & 15, quad = lane >> 4;
  const int bid = blockIdx.x;
  const int bh = bid & 31, qh = bid >> 5;  // bid%8 = bh%8: KV L2-local per XCD
  const int b = bh >> 3, h = bh & 7;
  const int khalf = w >> 2, strip = w & 3;
  const int qbase = qh * 256 + strip * 64;

  // Q frags once (packed head layout -> contiguous loads).
  const unsigned short* Qp =
      QH + ((size_t)bh * 4096 + qbase + l15) * 32 + quad * 8;
  short8 qf[4];
#pragma unroll
  for (int s = 0; s < 4; s++) qf[s] = *(const short8*)(Qp + (size_t)s * 512);

  // Staging setup (per lane global src; wave-uniform LDS base). R4-identical.
  const bool isK = (w < 4);
  const unsigned short* src0;
  int kstr, wbOff;
  if (isK) {
    const int key = w * 16 + (lane >> 2);
    const int gseg = (lane & 3) ^ ((lane >> 3) & 3);  // seg ^ ((key>>1)&3)
    src0 = KH + ((size_t)bh * 4096 + key) * 32 + gseg * 8;
    kstr = 32;          // shorts per key step
    wbOff = w * 1024;   // K region
  } else {
    const int r = (w - 4) * 8 + (lane >> 3), useg = lane & 7;
    src0 = VT + ((size_t)bh * 32 + r) * 4096 + ((useg ^ (r & 7)) * 8);
    kstr = 1;
    wbOff = 4096 + (w - 4) * 1024;  // V region
  }

  async_cp16(src0, smem + wbOff);  // preload tile 0 -> buf 0
  __syncthreads();

  const f32x4 zero = {0.f, 0.f, 0.f, 0.f};
  f32x4 acc[4][2];  // partial O^T over key-half: col=q=l15, row=d
#pragma unroll
  for (int s = 0; s < 4; s++) {
    acc[s][0] = zero;
    acc[s][1] = zero;
  }

  const int rs = l15 & 7;
  const int kseg = (quad ^ ((l15 >> 1) & 3)) * 16;  // K-tile read de-swizzle
  const int voff = ((khalf * 4 + quad) ^ rs) * 16;  // V frag: u = khalf
  for (int i = 0; i < 64; i++) {
    const int nb = i & 1;
    const int kn = ((i + 1) & 63) * 64;  // next key base (wraps, in-bounds)
    async_cp16(src0 + (size_t)kn * kstr, smem + (nb ^ 1) * 8192 + wbOff);

    const char* Kb = smem + nb * 8192;
    const char* Vb = Kb + 4096;
    short8 kf[2];  // this wave's key-half only: rows khalf*32 + c*16 + l15
#pragma unroll
    for (int c = 0; c < 2; c++)
      kf[c] = *(const short8*)(Kb + ((khalf * 32 + c * 16 + l15) * 64) + kseg);
    short8 vf[2];  // [dt]: V^T rows dt*16+l15, VT-order keys khalf*32+quad*8..
#pragma unroll
    for (int dt = 0; dt < 2; dt++)
      vf[dt] = *(const short8*)(Vb + (dt * 16 + l15) * 128 + voff);

#pragma unroll
    for (int s = 0; s < 4; s++) {
      u32x4 bw;  // packed P in B-frag order: slot k=quad*8+j
#pragma unroll
      for (int c = 0; c < 2; c++) {
        f32x4 st = MFMA16x32(kf[c], qf[s], zero);  // S^T 16key x 16q
        bw[2 * c] = leaky_pack(st[0], st[1]);  // Q pre-scaled by 1/sqrt(dk)
        bw[2 * c + 1] = leaky_pack(st[2], st[3]);
      }
      // B-frag slot k=quad*8+j holds phys key khalf*32+16*(j>>2)+4*quad+(j&3)
      // == VT-order key khalf*32+quad*8+j (by the VT permutation).
      short8 pb = __builtin_bit_cast(short8, bw);
#pragma unroll
      for (int dt = 0; dt < 2; dt++)
        acc[s][dt] = MFMA16x32(vf[dt], pb, acc[s][dt]);
    }
    __syncthreads();
  }

  // Split-K reduce: khalf=1 waves write partial O to LDS; khalf=0 add+store.
  // Region: strip*8KB + slot*1KB + lane*16B  (4 strips x 8 slots x 1KB = 32KB)
  if (khalf) {
    char* dst = smem + strip * 8192 + lane * 16;
#pragma unroll
    for (int s = 0; s < 4; s++)
#pragma unroll
      for (int dt = 0; dt < 2; dt++)
        *(f32x4*)(dst + (s * 2 + dt) * 1024) = acc[s][dt];
  }
  __syncthreads();
  if (!khalf) {
    const char* srcp = smem + strip * 8192 + lane * 16;
#pragma unroll
    for (int s = 0; s < 4; s++)
#pragma unroll
      for (int dt = 0; dt < 2; dt++) {
        f32x4 o = *(const f32x4*)(srcp + (s * 2 + dt) * 1024);
        o += acc[s][dt];
        // out[b][q][h*32+d]; lane q=l15(+16s), d=dt*16+quad*4..+4.
        *(f32x4*)(out + ((size_t)b * 4096 + qbase + s * 16 + l15) * 256 +
                  h * 32 + dt * 16 + quad * 4) = o;
      }
  }
}

// ---------------------------------------------------------------------------
extern "C" void kernel_launch(void* const* d_in, const int* in_sizes, int n_in,
                              void* d_out, int out_size, void* d_ws,
                              size_t ws_size, hipStream_t stream) {
  const float* x = (const float*)d_in[0];
  const float* Wq = (const float*)d_in[1];
  const float* Wk = (const float*)d_in[2];
  const float* Wv = (const float*)d_in[3];
  float* out = (float*)d_out;

  // Workspace (bf16): QH | KH | VT | xb | WT   (~33.9 MB)
  unsigned short* ws = (unsigned short*)d_ws;
  unsigned short* QHb = ws;                // 32 bh * 4096 n * 32 d
  unsigned short* KHb = ws + 4194304;      // 32 bh * 4096 n * 32 d
  unsigned short* VTb = ws + 2 * 4194304;  // 32 bh * 32 d * 4096 n (permuted)
  unsigned short* xbb = ws + 3 * 4194304;  // 16384*256
  unsigned short* WTb = ws + 4 * 4194304;  // 3 * 256 * 256

  prep_kernel<<<4288, 256, 0, stream>>>(x, xbb, Wq, Wk, Wv, WTb);
  proj_kernel<<<768, 256, 0, stream>>>(xbb, WTb, QHb, KHb, VTb);
  attn_kernel<<<512, 512, 0, stream>>>(QHb, KHb, VTb, out);
}